// Round 2
// baseline (299.365 us; speedup 1.0000x reference)
//
#include <hip/hip_runtime.h>
#include <stdint.h>

// B=32, Cin=128, T=4096, K=4, Cout=256, ks=7, pad=3
// Fold softmax routing into per-batch bf16 weights; barrier-free MFMA K-loop:
// x tile resident in LDS, W streamed global->VGPR in wave-fragment order.

#define TP 4102   // 4096 + 6 halo rows (3 each side), zero-padded

// workspace offsets (bytes)
#define XT_OFF     0u            // bf16 x planes [b][g=16][TP][8ci]  -> 33,603,584 B
#define WEFF_OFF   33603584u     // bf16 folded W, wave-fragment tiled -> 14,680,064 B
#define POOLED_OFF 48283648u     // fp32 [32][128]
#define ALPHA_OFF  48300032u     // fp32 [32][4]
#define BIAS_OFF   48300544u     // fp32 [32][256]

typedef short short8 __attribute__((ext_vector_type(8)));
typedef float f32x4 __attribute__((ext_vector_type(4)));

__device__ __forceinline__ unsigned short f2bf(float f) {
  unsigned int u = __builtin_bit_cast(unsigned int, f);
  u += 0x7fffu + ((u >> 16) & 1u);   // RNE
  return (unsigned short)(u >> 16);
}

// ---------------------------------------------------------------------------
// Kernel 1: x [b][ci][t] fp32 -> bf16 planes xt[b][g][3+t][8ci] (halo zeroed),
// plus pooled[b][ci] partial sums (atomicAdd onto memset-zeroed buffer).
// ---------------------------------------------------------------------------
__global__ __launch_bounds__(256) void k_transpose_pool(
    const float* __restrict__ x, unsigned short* __restrict__ xt,
    float* __restrict__ pooled) {
  __shared__ __align__(16) unsigned short xs[128 * 136]; // [ci][t]
  __shared__ float pbuf[128 * 33];
  int blk = blockIdx.x;
  int b = blk >> 5, tc = blk & 31;
  int t0 = tc << 7;
  int tid = threadIdx.x;
  int lane32 = tid & 31, grp8 = tid >> 5;

  #pragma unroll
  for (int i = 0; i < 16; ++i) {
    int ci = i * 8 + grp8;
    const float4 v = *(const float4*)(x + (size_t)(b * 128 + ci) * 4096 + t0 + lane32 * 4);
    unsigned short h0 = f2bf(v.x), h1 = f2bf(v.y), h2 = f2bf(v.z), h3 = f2bf(v.w);
    uint2 pk;
    pk.x = (unsigned)h0 | ((unsigned)h1 << 16);
    pk.y = (unsigned)h2 | ((unsigned)h3 << 16);
    *(uint2*)(&xs[ci * 136 + lane32 * 4]) = pk;
    pbuf[ci * 33 + lane32] = v.x + v.y + v.z + v.w;
  }
  __syncthreads();
  if (tid < 128) {
    float s = 0.f;
    #pragma unroll
    for (int l = 0; l < 32; ++l) s += pbuf[tid * 33 + l];
    atomicAdd(&pooled[b * 128 + tid], s);
  }
  #pragma unroll
  for (int it = 0; it < 8; ++it) {
    int idx = it * 256 + tid;      // 2048 = 128 tr x 16 g
    int tr = idx & 127, g = idx >> 7;
    unsigned short h[8];
    #pragma unroll
    for (int u = 0; u < 8; ++u) h[u] = xs[(g * 8 + u) * 136 + tr];
    uint4 o;
    o.x = (unsigned)h[0] | ((unsigned)h[1] << 16);
    o.y = (unsigned)h[2] | ((unsigned)h[3] << 16);
    o.z = (unsigned)h[4] | ((unsigned)h[5] << 16);
    o.w = (unsigned)h[6] | ((unsigned)h[7] << 16);
    *(uint4*)(xt + ((size_t)(b * 16 + g) * TP + 3 + t0 + tr) * 8) = o;
  }
  uint4 z; z.x = z.y = z.z = z.w = 0;
  if (tc == 0 && tid < 64) {
    int g = tid >> 2, pr = tid & 3;
    if (pr < 3) *(uint4*)(xt + ((size_t)(b * 16 + g) * TP + pr) * 8) = z;
  }
  if (tc == 31 && tid < 64) {
    int g = tid >> 2, pr = tid & 3;
    if (pr < 3) *(uint4*)(xt + ((size_t)(b * 16 + g) * TP + 4099 + pr) * 8) = z;
  }
}

// ---------------------------------------------------------------------------
// Kernel 2: alpha = softmax(pooled/T @ rw^T + rb), bias_eff = alpha @ bias
// ---------------------------------------------------------------------------
__global__ __launch_bounds__(128) void k_alpha(
    const float* __restrict__ pooled, const float* __restrict__ rw,
    const float* __restrict__ rb, const float* __restrict__ bias,
    float* __restrict__ alpha, float* __restrict__ bias_eff) {
  __shared__ float red[4][128];
  __shared__ float al[4];
  int b = blockIdx.x, tid = threadIdx.x;
  float p = pooled[b * 128 + tid] * (1.0f / 4096.0f);
  #pragma unroll
  for (int k = 0; k < 4; ++k) red[k][tid] = p * rw[k * 128 + tid];
  __syncthreads();
  if (tid < 4) {
    float s = rb[tid];
    for (int j = 0; j < 128; ++j) s += red[tid][j];
    red[tid][0] = s;
  }
  __syncthreads();
  if (tid == 0) {
    float m = red[0][0];
    for (int k = 1; k < 4; ++k) m = fmaxf(m, red[k][0]);
    float e0 = __expf(red[0][0] - m), e1 = __expf(red[1][0] - m);
    float e2 = __expf(red[2][0] - m), e3 = __expf(red[3][0] - m);
    float inv = 1.0f / (e0 + e1 + e2 + e3);
    al[0] = e0 * inv; al[1] = e1 * inv; al[2] = e2 * inv; al[3] = e3 * inv;
    #pragma unroll
    for (int k = 0; k < 4; ++k) alpha[b * 4 + k] = al[k];
  }
  __syncthreads();
  #pragma unroll
  for (int cc = 0; cc < 2; ++cc) {
    int c = cc * 128 + tid;
    float s = 0.f;
    #pragma unroll
    for (int k = 0; k < 4; ++k) s += al[k] * bias[k * 256 + c];
    bias_eff[b * 256 + c] = s;
  }
}

// ---------------------------------------------------------------------------
// Kernel 3: fold alpha into W (reading original [k][cout][ci][s] layout),
// cast bf16, store in wave-fragment order so k_conv A-loads are 1KB coalesced:
//   weff[((bcb*28 + step)*8 + cblk)*64 + lane][8], lane = q*16+n16,
//   step = chunk*2+kk, chunk=(s,half); c = cblk*16+n16, ci0 = half*64+(kk*4+q)*8
// ---------------------------------------------------------------------------
__global__ __launch_bounds__(256) void k_fold(const float* __restrict__ w,
                                              const float* __restrict__ alpha,
                                              unsigned short* __restrict__ weff) {
  int idx = blockIdx.x * 256 + threadIdx.x;  // 917504 exact
  int n16 = idx & 15;
  int q = (idx >> 4) & 3;
  int cblk = (idx >> 6) & 7;
  int kk = (idx >> 9) & 1;
  int rest = idx >> 10;          // 0..895
  int chunk = rest % 14;
  int bcb = rest / 14;
  int cb = bcb & 1, b = bcb >> 1;
  int s = chunk >> 1, half = chunk & 1;
  int cout = cb * 128 + cblk * 16 + n16;
  int ci0 = half * 64 + (kk * 4 + q) * 8;
  float a[4];
  #pragma unroll
  for (int k = 0; k < 4; ++k) a[k] = alpha[b * 4 + k];
  float acc8[8];
  #pragma unroll
  for (int j = 0; j < 8; ++j) acc8[j] = 0.f;
  #pragma unroll
  for (int k = 0; k < 4; ++k) {
    const float* src = w + ((size_t)(k * 256 + cout) * 128 + ci0) * 7 + s;
    #pragma unroll
    for (int j = 0; j < 8; ++j) acc8[j] += a[k] * src[j * 7];
  }
  unsigned short h[8];
  #pragma unroll
  for (int j = 0; j < 8; ++j) h[j] = f2bf(acc8[j]);
  uint4 o;
  o.x = (unsigned)h[0] | ((unsigned)h[1] << 16);
  o.y = (unsigned)h[2] | ((unsigned)h[3] << 16);
  o.z = (unsigned)h[4] | ((unsigned)h[5] << 16);
  o.w = (unsigned)h[6] | ((unsigned)h[7] << 16);
  *(uint4*)(weff + (size_t)idx * 8) = o;
}

// ---------------------------------------------------------------------------
// Kernel 4: conv as implicit GEMM, barrier-free K-loop.
// Block = 128 cout x 128 t for one (b,cb). x tile in LDS [g][136 rows][8ci];
// W streamed global->VGPR (coalesced 1KB fragment loads, L2-resident),
// one-step-ahead prefetch. 4 waves 2x2, each 64x64 via 4x4 mfma 16x16x32.
// ---------------------------------------------------------------------------
__global__ __launch_bounds__(256, 4) void k_conv(
    const unsigned short* __restrict__ xt, const unsigned short* __restrict__ weff,
    const float* __restrict__ bias_eff, float* __restrict__ out) {
  __shared__ __align__(16) unsigned short xs[16 * 136 * 8];  // 34,816 B -> 4 blk/CU
  int blk = blockIdx.x;
  int b = blk >> 6, cb = (blk >> 5) & 1, tb = blk & 31;
  int bcb = b * 2 + cb;
  int tid = threadIdx.x;
  int wave = tid >> 6, lane = tid & 63;
  int q = lane >> 4, n16 = lane & 15;
  int wm = wave & 1, wn = wave >> 1;
  int t00 = tb << 7;

  // stage x tile: 134 rows x 16 g-planes of 16B, coalesced
  const unsigned short* xtb = xt + (size_t)b * 16 * TP * 8;
  #pragma unroll
  for (int it = 0; it < 8; ++it) {
    int idx = it * 256 + tid;
    int g = idx >> 7, row = idx & 127;
    uint4 v = *(const uint4*)(xtb + ((size_t)g * TP + t00 + row) * 8);
    *(uint4*)(&xs[(g * 136 + row) * 8]) = v;
  }
  if (tid < 128) {
    int g = tid >> 3, r8 = tid & 7;
    if (r8 < 6) {
      int row = 128 + r8;
      uint4 v = *(const uint4*)(xtb + ((size_t)g * TP + t00 + row) * 8);
      *(uint4*)(&xs[(g * 136 + row) * 8]) = v;
    }
  }
  __syncthreads();

  f32x4 acc[4][4];
  #pragma unroll
  for (int mi = 0; mi < 4; ++mi)
    #pragma unroll
    for (int ni = 0; ni < 4; ++ni)
      acc[mi][ni] = (f32x4){0.f, 0.f, 0.f, 0.f};

  // W fragment pointer: short8 units; step*512 + mi*64 offsets are linear.
  const short8* wfrag = (const short8*)weff + (size_t)bcb * 14336 + (wm * 4) * 64 + lane;

  short8 av[4];
  #pragma unroll
  for (int mi = 0; mi < 4; ++mi) av[mi] = wfrag[mi * 64];

  #pragma unroll 2
  for (int step = 0; step < 28; ++step) {
    int s = step >> 2, half = (step >> 1) & 1, kk = step & 1;
    short8 avn[4];
    if (step < 27) {
      #pragma unroll
      for (int mi = 0; mi < 4; ++mi)
        avn[mi] = wfrag[(step + 1) * 512 + mi * 64];
    }
    short8 bv[4];
    #pragma unroll
    for (int ni = 0; ni < 4; ++ni) {
      int tt = wn * 64 + ni * 16 + n16;
      bv[ni] = *(const short8*)(&xs[((half * 8 + kk * 4 + q) * 136 + tt + s) * 8]);
    }
    #pragma unroll
    for (int mi = 0; mi < 4; ++mi)
      #pragma unroll
      for (int ni = 0; ni < 4; ++ni)
        acc[mi][ni] = __builtin_amdgcn_mfma_f32_16x16x32_bf16(
            av[mi], bv[ni], acc[mi][ni], 0, 0, 0);
    #pragma unroll
    for (int mi = 0; mi < 4; ++mi) av[mi] = avn[mi];
  }

  // epilogue: D layout col(lane&15)=t, row(q*4+r)=cout
  int crow0 = b * 256 + cb * 128;
  #pragma unroll
  for (int mi = 0; mi < 4; ++mi) {
    #pragma unroll
    for (int r = 0; r < 4; ++r) {
      int c = wm * 64 + mi * 16 + q * 4 + r;
      float bb = bias_eff[crow0 + c];
      float* orow = out + (size_t)(crow0 + c) * 4096 + t00;
      #pragma unroll
      for (int ni = 0; ni < 4; ++ni)
        orow[wn * 64 + ni * 16 + n16] = acc[mi][ni][r] + bb;
    }
  }
}

extern "C" void kernel_launch(void* const* d_in, const int* in_sizes, int n_in,
                              void* d_out, int out_size, void* d_ws, size_t ws_size,
                              hipStream_t stream) {
  const float* x    = (const float*)d_in[0];
  const float* w    = (const float*)d_in[1];
  const float* bias = (const float*)d_in[2];
  const float* rw   = (const float*)d_in[3];
  const float* rb   = (const float*)d_in[4];
  float* out = (float*)d_out;
  char* ws = (char*)d_ws;
  unsigned short* xt   = (unsigned short*)(ws + XT_OFF);
  unsigned short* weff = (unsigned short*)(ws + WEFF_OFF);
  float* pooled        = (float*)(ws + POOLED_OFF);
  float* alpha         = (float*)(ws + ALPHA_OFF);
  float* bias_eff      = (float*)(ws + BIAS_OFF);

  hipMemsetAsync(pooled, 0, 32 * 128 * sizeof(float), stream);
  hipLaunchKernelGGL(k_transpose_pool, dim3(1024), dim3(256), 0, stream, x, xt, pooled);
  hipLaunchKernelGGL(k_alpha, dim3(32),   dim3(128), 0, stream, pooled, rw, rb, bias, alpha, bias_eff);
  hipLaunchKernelGGL(k_fold,  dim3(3584), dim3(256), 0, stream, w, alpha, weff);
  hipLaunchKernelGGL(k_conv,  dim3(2048), dim3(256), 0, stream, xt, weff, bias_eff, out);
}

// Round 3
// 252.158 us; speedup vs baseline: 1.1872x; 1.1872x over previous
//
#include <hip/hip_runtime.h>
#include <stdint.h>

// B=32, Cin=128, T=4096, K=4, Cout=256, ks=7, pad=3
// Fold softmax routing into per-batch bf16 weights; barrier-free MFMA K-loop:
// x tile resident in LDS, W streamed global->VGPR in wave-fragment order.

#define TP 4102   // 4096 + 6 halo rows (3 each side), zero-padded

// workspace offsets (bytes)
#define XT_OFF     0u            // bf16 x planes [b][g=16][TP][8ci]  -> 33,603,584 B
#define WEFF_OFF   33603584u     // bf16 folded W, wave-fragment tiled -> 14,680,064 B
#define WT_OFF     48283648u     // fp32 w transposed [k][cout][s][ci] -> 3,670,016 B
#define POOLED_OFF 51953664u     // fp32 [32][128]
#define ALPHA_OFF  51970048u     // fp32 [32][4]
#define BIAS_OFF   51970560u     // fp32 [32][256]

typedef short short8 __attribute__((ext_vector_type(8)));
typedef float f32x4 __attribute__((ext_vector_type(4)));

__device__ __forceinline__ unsigned short f2bf(float f) {
  unsigned int u = __builtin_bit_cast(unsigned int, f);
  u += 0x7fffu + ((u >> 16) & 1u);   // RNE
  return (unsigned short)(u >> 16);
}

// ---------------------------------------------------------------------------
// Kernel 1: x [b][ci][t] fp32 -> bf16 planes xt[b][g][3+t][8ci] (halo zeroed),
// plus pooled[b][ci] partial sums (atomicAdd onto memset-zeroed buffer).
// ---------------------------------------------------------------------------
__global__ __launch_bounds__(256) void k_transpose_pool(
    const float* __restrict__ x, unsigned short* __restrict__ xt,
    float* __restrict__ pooled) {
  __shared__ __align__(16) unsigned short xs[128 * 136]; // [ci][t]
  __shared__ float pbuf[128 * 33];
  int blk = blockIdx.x;
  int b = blk >> 5, tc = blk & 31;
  int t0 = tc << 7;
  int tid = threadIdx.x;
  int lane32 = tid & 31, grp8 = tid >> 5;

  #pragma unroll
  for (int i = 0; i < 16; ++i) {
    int ci = i * 8 + grp8;
    const float4 v = *(const float4*)(x + (size_t)(b * 128 + ci) * 4096 + t0 + lane32 * 4);
    unsigned short h0 = f2bf(v.x), h1 = f2bf(v.y), h2 = f2bf(v.z), h3 = f2bf(v.w);
    uint2 pk;
    pk.x = (unsigned)h0 | ((unsigned)h1 << 16);
    pk.y = (unsigned)h2 | ((unsigned)h3 << 16);
    *(uint2*)(&xs[ci * 136 + lane32 * 4]) = pk;
    pbuf[ci * 33 + lane32] = v.x + v.y + v.z + v.w;
  }
  __syncthreads();
  if (tid < 128) {
    float s = 0.f;
    #pragma unroll
    for (int l = 0; l < 32; ++l) s += pbuf[tid * 33 + l];
    atomicAdd(&pooled[b * 128 + tid], s);
  }
  #pragma unroll
  for (int it = 0; it < 8; ++it) {
    int idx = it * 256 + tid;      // 2048 = 128 tr x 16 g
    int tr = idx & 127, g = idx >> 7;
    unsigned short h[8];
    #pragma unroll
    for (int u = 0; u < 8; ++u) h[u] = xs[(g * 8 + u) * 136 + tr];
    uint4 o;
    o.x = (unsigned)h[0] | ((unsigned)h[1] << 16);
    o.y = (unsigned)h[2] | ((unsigned)h[3] << 16);
    o.z = (unsigned)h[4] | ((unsigned)h[5] << 16);
    o.w = (unsigned)h[6] | ((unsigned)h[7] << 16);
    *(uint4*)(xt + ((size_t)(b * 16 + g) * TP + 3 + t0 + tr) * 8) = o;
  }
  uint4 z; z.x = z.y = z.z = z.w = 0;
  if (tc == 0 && tid < 64) {
    int g = tid >> 2, pr = tid & 3;
    if (pr < 3) *(uint4*)(xt + ((size_t)(b * 16 + g) * TP + pr) * 8) = z;
  }
  if (tc == 31 && tid < 64) {
    int g = tid >> 2, pr = tid & 3;
    if (pr < 3) *(uint4*)(xt + ((size_t)(b * 16 + g) * TP + 4099 + pr) * 8) = z;
  }
}

// ---------------------------------------------------------------------------
// Kernel 2: weight [k][cout][ci][s] -> wt [k][cout][s][ci] fp32 (coalesced writes)
// ---------------------------------------------------------------------------
__global__ __launch_bounds__(256) void k_wt(const float* __restrict__ w,
                                            float* __restrict__ wt) {
  int gid = blockIdx.x * 256 + threadIdx.x;  // 131072 = 4*256*128
  int ci = gid & 127;
  int kc = gid >> 7;                         // k*256+cout
  const float* src = w + (size_t)gid * 7;
  #pragma unroll
  for (int s = 0; s < 7; ++s)
    wt[((size_t)kc * 7 + s) * 128 + ci] = src[s];
}

// ---------------------------------------------------------------------------
// Kernel 3: alpha = softmax(pooled/T @ rw^T + rb), bias_eff = alpha @ bias
// ---------------------------------------------------------------------------
__global__ __launch_bounds__(128) void k_alpha(
    const float* __restrict__ pooled, const float* __restrict__ rw,
    const float* __restrict__ rb, const float* __restrict__ bias,
    float* __restrict__ alpha, float* __restrict__ bias_eff) {
  __shared__ float red[4][128];
  __shared__ float al[4];
  int b = blockIdx.x, tid = threadIdx.x;
  float p = pooled[b * 128 + tid] * (1.0f / 4096.0f);
  #pragma unroll
  for (int k = 0; k < 4; ++k) red[k][tid] = p * rw[k * 128 + tid];
  __syncthreads();
  if (tid < 4) {
    float s = rb[tid];
    for (int j = 0; j < 128; ++j) s += red[tid][j];
    red[tid][0] = s;
  }
  __syncthreads();
  if (tid == 0) {
    float m = red[0][0];
    for (int k = 1; k < 4; ++k) m = fmaxf(m, red[k][0]);
    float e0 = __expf(red[0][0] - m), e1 = __expf(red[1][0] - m);
    float e2 = __expf(red[2][0] - m), e3 = __expf(red[3][0] - m);
    float inv = 1.0f / (e0 + e1 + e2 + e3);
    al[0] = e0 * inv; al[1] = e1 * inv; al[2] = e2 * inv; al[3] = e3 * inv;
    #pragma unroll
    for (int k = 0; k < 4; ++k) alpha[b * 4 + k] = al[k];
  }
  __syncthreads();
  #pragma unroll
  for (int cc = 0; cc < 2; ++cc) {
    int c = cc * 128 + tid;
    float s = 0.f;
    #pragma unroll
    for (int k = 0; k < 4; ++k) s += al[k] * bias[k * 256 + c];
    bias_eff[b * 256 + c] = s;
  }
}

// ---------------------------------------------------------------------------
// Kernel 4: fold alpha into wt (coalesced 256B-run reads), cast bf16, store in
// wave-fragment order for k_conv:
//   weff_short8[((bcb*28 + step)*8 + cblk)*64 + q*16 + n16], step=chunk*2+kk,
//   where cout = cb*128 + cblk*16 + n16, ci = half*64 + (kk*4+q)*8 + j.
// ---------------------------------------------------------------------------
__global__ __launch_bounds__(256) void k_fold(const float* __restrict__ wt,
                                              const float* __restrict__ alpha,
                                              unsigned short* __restrict__ weff) {
  int idx = blockIdx.x * 256 + threadIdx.x;  // 917504 exact
  int g = idx & 7;                // ci-group within 64-half (reads contiguous)
  int c = (idx >> 3) & 127;       // cout within cb
  int rest = idx >> 10;           // 0..895
  int chunk = rest % 14;
  int bcb = rest / 14;            // b*2+cb
  int cb = bcb & 1, b = bcb >> 1;
  int s = chunk >> 1, half = chunk & 1;
  int cout = cb * 128 + c;
  float a[4];
  #pragma unroll
  for (int k = 0; k < 4; ++k) a[k] = alpha[b * 4 + k];
  float acc8[8];
  #pragma unroll
  for (int j = 0; j < 8; ++j) acc8[j] = 0.f;
  #pragma unroll
  for (int k = 0; k < 4; ++k) {
    const float* src = wt + (((size_t)(k * 256 + cout) * 7 + s) * 128 + half * 64 + g * 8);
    #pragma unroll
    for (int j = 0; j < 8; ++j) acc8[j] += a[k] * src[j];
  }
  unsigned short h[8];
  #pragma unroll
  for (int j = 0; j < 8; ++j) h[j] = f2bf(acc8[j]);
  uint4 o;
  o.x = (unsigned)h[0] | ((unsigned)h[1] << 16);
  o.y = (unsigned)h[2] | ((unsigned)h[3] << 16);
  o.z = (unsigned)h[4] | ((unsigned)h[5] << 16);
  o.w = (unsigned)h[6] | ((unsigned)h[7] << 16);
  // fragment-layout store
  int kk = g >> 2, q = g & 3;
  int cblk = c >> 4, n16 = c & 15;
  int step = chunk * 2 + kk;
  size_t off8 = ((size_t)(bcb * 28 + step) * 8 + cblk) * 64 + q * 16 + n16;
  *(uint4*)(weff + off8 * 8) = o;
}

// ---------------------------------------------------------------------------
// Kernel 5: conv as implicit GEMM, barrier-free K-loop.
// Block = 128 cout x 128 t for one (b,cb). x tile in LDS [g][136 rows][8ci];
// W streamed global->VGPR (coalesced 1KB fragment loads, L2-resident),
// one-step-ahead prefetch. 4 waves 2x2, each 64x64 via 4x4 mfma 16x16x32.
// ---------------------------------------------------------------------------
__global__ __launch_bounds__(256, 4) void k_conv(
    const unsigned short* __restrict__ xt, const unsigned short* __restrict__ weff,
    const float* __restrict__ bias_eff, float* __restrict__ out) {
  __shared__ __align__(16) unsigned short xs[16 * 136 * 8];  // 34,816 B -> 4 blk/CU
  int blk = blockIdx.x;
  int b = blk >> 6, cb = (blk >> 5) & 1, tb = blk & 31;
  int bcb = b * 2 + cb;
  int tid = threadIdx.x;
  int wave = tid >> 6, lane = tid & 63;
  int q = lane >> 4, n16 = lane & 15;
  int wm = wave & 1, wn = wave >> 1;
  int t00 = tb << 7;

  // stage x tile: 134 rows x 16 g-planes of 16B, coalesced
  const unsigned short* xtb = xt + (size_t)b * 16 * TP * 8;
  #pragma unroll
  for (int it = 0; it < 8; ++it) {
    int idx = it * 256 + tid;
    int g = idx >> 7, row = idx & 127;
    uint4 v = *(const uint4*)(xtb + ((size_t)g * TP + t00 + row) * 8);
    *(uint4*)(&xs[(g * 136 + row) * 8]) = v;
  }
  if (tid < 128) {
    int g = tid >> 3, r8 = tid & 7;
    if (r8 < 6) {
      int row = 128 + r8;
      uint4 v = *(const uint4*)(xtb + ((size_t)g * TP + t00 + row) * 8);
      *(uint4*)(&xs[(g * 136 + row) * 8]) = v;
    }
  }
  __syncthreads();

  f32x4 acc[4][4];
  #pragma unroll
  for (int mi = 0; mi < 4; ++mi)
    #pragma unroll
    for (int ni = 0; ni < 4; ++ni)
      acc[mi][ni] = (f32x4){0.f, 0.f, 0.f, 0.f};

  // W fragment pointer: short8 units; step*512 + mi*64 offsets are linear.
  const short8* wfrag = (const short8*)weff + (size_t)bcb * 14336 + (wm * 4) * 64 + lane;

  short8 av[4];
  #pragma unroll
  for (int mi = 0; mi < 4; ++mi) av[mi] = wfrag[mi * 64];

  #pragma unroll 2
  for (int step = 0; step < 28; ++step) {
    int s = step >> 2, half = (step >> 1) & 1, kk = step & 1;
    short8 avn[4];
    if (step < 27) {
      #pragma unroll
      for (int mi = 0; mi < 4; ++mi)
        avn[mi] = wfrag[(step + 1) * 512 + mi * 64];
    }
    short8 bv[4];
    #pragma unroll
    for (int ni = 0; ni < 4; ++ni) {
      int tt = wn * 64 + ni * 16 + n16;
      bv[ni] = *(const short8*)(&xs[((half * 8 + kk * 4 + q) * 136 + tt + s) * 8]);
    }
    #pragma unroll
    for (int mi = 0; mi < 4; ++mi)
      #pragma unroll
      for (int ni = 0; ni < 4; ++ni)
        acc[mi][ni] = __builtin_amdgcn_mfma_f32_16x16x32_bf16(
            av[mi], bv[ni], acc[mi][ni], 0, 0, 0);
    #pragma unroll
    for (int mi = 0; mi < 4; ++mi) av[mi] = avn[mi];
  }

  // epilogue: D layout col(lane&15)=t, row(q*4+r)=cout
  int crow0 = b * 256 + cb * 128;
  #pragma unroll
  for (int mi = 0; mi < 4; ++mi) {
    #pragma unroll
    for (int r = 0; r < 4; ++r) {
      int c = wm * 64 + mi * 16 + q * 4 + r;
      float bb = bias_eff[crow0 + c];
      float* orow = out + (size_t)(crow0 + c) * 4096 + t00;
      #pragma unroll
      for (int ni = 0; ni < 4; ++ni)
        orow[wn * 64 + ni * 16 + n16] = acc[mi][ni][r] + bb;
    }
  }
}

extern "C" void kernel_launch(void* const* d_in, const int* in_sizes, int n_in,
                              void* d_out, int out_size, void* d_ws, size_t ws_size,
                              hipStream_t stream) {
  const float* x    = (const float*)d_in[0];
  const float* w    = (const float*)d_in[1];
  const float* bias = (const float*)d_in[2];
  const float* rw   = (const float*)d_in[3];
  const float* rb   = (const float*)d_in[4];
  float* out = (float*)d_out;
  char* ws = (char*)d_ws;
  unsigned short* xt   = (unsigned short*)(ws + XT_OFF);
  unsigned short* weff = (unsigned short*)(ws + WEFF_OFF);
  float* wt            = (float*)(ws + WT_OFF);
  float* pooled        = (float*)(ws + POOLED_OFF);
  float* alpha         = (float*)(ws + ALPHA_OFF);
  float* bias_eff      = (float*)(ws + BIAS_OFF);

  hipMemsetAsync(pooled, 0, 32 * 128 * sizeof(float), stream);
  hipLaunchKernelGGL(k_transpose_pool, dim3(1024), dim3(256), 0, stream, x, xt, pooled);
  hipLaunchKernelGGL(k_wt,    dim3(512),  dim3(256), 0, stream, w, wt);
  hipLaunchKernelGGL(k_alpha, dim3(32),   dim3(128), 0, stream, pooled, rw, rb, bias, alpha, bias_eff);
  hipLaunchKernelGGL(k_fold,  dim3(3584), dim3(256), 0, stream, wt, alpha, weff);
  hipLaunchKernelGGL(k_conv,  dim3(2048), dim3(256), 0, stream, xt, weff, bias_eff, out);
}